// Round 11
// baseline (190.826 us; speedup 1.0000x reference)
//
#include <hip/hip_runtime.h>
#include <math.h>

#define T_LEN 4096
#define C_CH  128
#define B_N   32
#define LT 16
#define TT 64
#define NT_BLK (T_LEN / TT)   // 64
#define HALO 80               // TT + 16 halo floats of t per block
#define LSTR 65               // LDS row stride in floats (64 c + 1 pad)

// ---------------- Kernel 1: per-(b,c) row mean, one wave per row ----------------
__global__ __launch_bounds__(256) void row_mean_kernel(const float* __restrict__ x,
                                                       float* __restrict__ means) {
    const int wid  = ((blockIdx.x << 8) + threadIdx.x) >> 6;    // global wave id = row
    const int lane = threadIdx.x & 63;
    const float4* r = (const float4*)(x + ((size_t)wid << 12)); // row base (4096 floats)
    float s = 0.f;
    #pragma unroll
    for (int i = 0; i < 16; ++i) {
        float4 v = r[lane + (i << 6)];
        s += (v.x + v.y) + (v.z + v.w);
    }
    #pragma unroll
    for (int off = 32; off > 0; off >>= 1) s += __shfl_down(s, off, 64);
    if (lane == 0) means[wid] = s * (1.0f / T_LEN);
}

// ---------------- Kernel 2: fused features + depthwise conv + epilogue ----------------
// Block: 256 threads = 64 channels (ci) x 4 t-groups (th); per thread 1 channel x 16 t.
// x-tile (64 c x 80 t) staged via LDS: global reads coalesced (320B runs),
// LDS transposed [t][c] stride 65 -> conflict-free reads (2 lanes/bank).
__global__ __launch_bounds__(256, 4) void fused_kernel(const float* __restrict__ x,
                                                       const float* __restrict__ w,
                                                       const float* __restrict__ bias,
                                                       const float* __restrict__ means,
                                                       float* __restrict__ out) {
    __shared__ float lds[HALO * LSTR];                  // 20800 B
    const int b    = blockIdx.z;
    const int cblk = blockIdx.y;
    const int tblk = blockIdx.x;
    const int tid  = threadIdx.x;
    const int T0   = tblk * TT;
    const float* xc0 = x + ((size_t)b * C_CH + cblk * 64) * T_LEN;

    const bool edge = (tblk == 0) || (tblk == NT_BLK - 1);

    // ---- stage: 64 rows(c) x 20 float4(t) = 1280 float4, 5 per thread ----
    #pragma unroll
    for (int k = 0; k < 5; ++k) {
        const int j  = tid + (k << 8);                  // 0..1279
        const int r  = j / 20;                          // c row 0..63
        const int q  = j - r * 20;                      // f4 index 0..19
        const int tg = T0 - 8 + (q << 2);               // global t of f4 start (mult of 4)
        float4 v;
        if (!edge || ((unsigned)tg < (unsigned)T_LEN)) { // tg in [0,4092] <=> f4 fully valid
            v = *(const float4*)(xc0 + (size_t)r * T_LEN + tg);
        } else {
            v.x = 0.f; v.y = 0.f; v.z = 0.f; v.w = 0.f; // zero-pad outside [0,T)
        }
        float* dst = &lds[(size_t)(tg - (T0 - 8)) * LSTR + r];
        dst[0 * LSTR] = v.x; dst[1 * LSTR] = v.y;
        dst[2 * LSTR] = v.z; dst[3 * LSTR] = v.w;
    }
    __syncthreads();

    const int ci = tid & 63;
    const int th = tid >> 6;
    const int c  = cblk * 64 + ci;
    const int ts = T0 + th * LT;

    const float mean = means[b * C_CH + c];
    const float bs   = bias[c];

    // weights w[c][h][k] as 15 float2
    float2 wv2[15];
    const float2* pw2 = (const float2*)(w + c * 30);
    #pragma unroll
    for (int i = 0; i < 15; ++i) wv2[i] = pw2[i];
    #define W(idx) (((idx) & 1) ? wv2[(idx) >> 1].y : wv2[(idx) >> 1].x)

    // va[i] = x[c][ts-8+i] (zeros outside [0,T)) from LDS; base + compile-time offsets
    float va[32];
    {
        const float* src = &lds[(size_t)(th * LT) * LSTR + ci];
        #pragma unroll
        for (int i = 0; i < 32; ++i) va[i] = src[i * LSTR];
    }

    float* po = out + ((size_t)(b * T_LEN + ts)) * C_CH + c;

    if (!edge) {
        // ---------- interior fast path: branch-free ----------
        const float w1s = ((W(5) + W(6)) + (W(7) + W(8))) + W(9);
        float acc[LT];
        #pragma unroll
        for (int i = 0; i < LT; ++i) acc[i] = fmaf(mean, w1s, bs);

        #pragma unroll
        for (int lj = 0; lj < LT + 4; ++lj) {           // feature position j = ts-2+lj
            const float v0 = va[lj+4], v1 = va[lj+5], v2 = va[lj+6], v3 = va[lj+7], v4 = va[lj+8];
            const float s  = ((v0 + v1) + (v2 + v3)) + v4;
            float s2 = v0 * v0;
            s2 = fmaf(v1, v1, s2); s2 = fmaf(v2, v2, s2);
            s2 = fmaf(v3, v3, s2); s2 = fmaf(v4, v4, s2);
            const float mx = fmaxf(fmaxf(fmaxf(v0, v1), fmaxf(v2, v3)), v4);
            const float mn = fminf(fminf(fminf(v0, v1), fminf(v2, v3)), v4);
            const float avg = s * 0.2f;
            float var = fmaf(-avg, avg, s2 * 0.2f);
            var = fmaxf(var, 1e-6f);
            const float sd = __builtin_amdgcn_sqrtf(var);
            const float dm = v2 - avg;
            const float tm = dm * dm * dm;

            #pragma unroll
            for (int dt = -2; dt <= 2; ++dt) {
                const int lt = lj - 2 + dt;             // compile-time after unroll
                if (lt < 0 || lt >= LT) continue;
                const int k = 2 - dt;
                float a = acc[lt];
                a = fmaf(v2, W(k),      a);
                a = fmaf(sd, W(10 + k), a);
                a = fmaf(tm, W(15 + k), a);
                a = fmaf(mx, W(20 + k), a);
                a = fmaf(mn, W(25 + k), a);
                acc[lt] = a;
            }
        }

        #pragma unroll
        for (int lt = 0; lt < LT; ++lt) {
            float o = acc[lt];
            o = fmaxf(o, 0.01f * o);                    // leaky relu
            po[lt * C_CH] = va[lt + 8] + o;             // residual + transposed store
        }
    } else {
        // ---------- edge path (tblk 0 / 63): fully guarded ----------
        float acc[LT];
        #pragma unroll
        for (int i = 0; i < LT; ++i) acc[i] = bs;

        #pragma unroll
        for (int lj = 0; lj < LT + 4; ++lj) {
            const int j = ts - 2 + lj;
            if (j < 0 || j >= T_LEN) continue;          // conv zero-pad: feature = 0
            float s = 0.f, s2 = 0.f, mx = -INFINITY, mn = INFINITY;
            #pragma unroll
            for (int d = -2; d <= 2; ++d) {
                int gk = j + d;
                if (gk >= 0 && gk < T_LEN) {            // pool validity
                    float v = va[lj + 6 + d];
                    s += v; s2 = fmaf(v, v, s2);
                    mx = fmaxf(mx, v); mn = fminf(mn, v);
                }
            }
            const float avg = s * 0.2f;                 // zero-padded avg: always /5
            float var = fmaf(-avg, avg, s2 * 0.2f);
            var = fmaxf(var, 1e-6f);
            const float sd = __builtin_amdgcn_sqrtf(var);
            const float xc = va[lj + 6];
            const float dm = xc - avg;
            const float tm = dm * dm * dm;

            #pragma unroll
            for (int dt = -2; dt <= 2; ++dt) {
                const int lt = lj - 2 + dt;
                if (lt < 0 || lt >= LT) continue;
                const int k = 2 - dt;
                float a = acc[lt];
                a = fmaf(xc,   W(k),      a);
                a = fmaf(mean, W(5 + k),  a);
                a = fmaf(sd,   W(10 + k), a);
                a = fmaf(tm,   W(15 + k), a);
                a = fmaf(mx,   W(20 + k), a);
                a = fmaf(mn,   W(25 + k), a);
                acc[lt] = a;
            }
        }

        #pragma unroll
        for (int lt = 0; lt < LT; ++lt) {
            float o = acc[lt];
            o = fmaxf(o, 0.01f * o);
            po[lt * C_CH] = va[lt + 8] + o;
        }
    }
    #undef W
}

extern "C" void kernel_launch(void* const* d_in, const int* in_sizes, int n_in,
                              void* d_out, int out_size, void* d_ws, size_t ws_size,
                              hipStream_t stream) {
    const float* x    = (const float*)d_in[0];
    const float* w    = (const float*)d_in[1];
    const float* bias = (const float*)d_in[2];
    float* means = (float*)d_ws;                        // 4096 floats
    float* out   = (float*)d_out;

    row_mean_kernel<<<dim3((B_N * C_CH) / 4), dim3(256), 0, stream>>>(x, means);
    fused_kernel<<<dim3(NT_BLK, C_CH / 64, B_N), dim3(256), 0, stream>>>(x, w, bias, means, out);
}

// Round 13
// 152.935 us; speedup vs baseline: 1.2478x; 1.2478x over previous
//
#include <hip/hip_runtime.h>
#include <math.h>

#define T_LEN 4096
#define C_CH  128
#define B_N   32
#define LT 8
#define TT 32                 // t per block = 4 waves * LT
#define NT_BLK (T_LEN / TT)   // 128

// ---------------- Kernel 1: per-(b,c) row mean, one wave per row ----------------
__global__ __launch_bounds__(256) void row_mean_kernel(const float* __restrict__ x,
                                                       float* __restrict__ means) {
    const int wid  = ((blockIdx.x << 8) + threadIdx.x) >> 6;    // global wave id = row
    const int lane = threadIdx.x & 63;
    const float4* r = (const float4*)(x + ((size_t)wid << 12)); // row base (4096 floats)
    float s = 0.f;
    #pragma unroll
    for (int i = 0; i < 16; ++i) {
        float4 v = r[lane + (i << 6)];
        s += (v.x + v.y) + (v.z + v.w);
    }
    #pragma unroll
    for (int off = 32; off > 0; off >>= 1) s += __shfl_down(s, off, 64);
    if (lane == 0) means[wid] = s * (1.0f / T_LEN);
}

// ---------------- Kernel 2: fused features + depthwise conv + epilogue ----------------
// Block: 256 threads = 64 channels (lane) x 4 t-groups (th). Each thread: 1 channel, 8 t.
// Same structure as the 44us R9 kernel; only LT halved (16->8) to double wave count
// for latency hiding of the per-lane scattered row reads.
__global__ __launch_bounds__(256, 4) void fused_kernel(const float* __restrict__ x,
                                                       const float* __restrict__ w,
                                                       const float* __restrict__ bias,
                                                       const float* __restrict__ means,
                                                       float* __restrict__ out) {
    const int b    = blockIdx.z;
    const int cblk = blockIdx.y;
    const int tblk = blockIdx.x;
    const int tid  = threadIdx.x;
    const int c    = cblk * 64 + (tid & 63);
    const int th   = tid >> 6;
    const int ts   = tblk * TT + th * LT;

    const float* xr  = x + ((size_t)(b * C_CH + c)) * T_LEN;
    const float mean = means[b * C_CH + c];
    const float bs   = bias[c];

    // weights w[c][h][k] as 15 float2
    float2 wv2[15];
    const float2* pw2 = (const float2*)(w + c * 30);
    #pragma unroll
    for (int i = 0; i < 15; ++i) wv2[i] = pw2[i];
    #define W(idx) (((idx) & 1) ? wv2[(idx) >> 1].y : wv2[(idx) >> 1].x)

    const int gbase = ts - 8;                           // mult of 8 -> 32B aligned
    float* po = out + ((size_t)(b * T_LEN + ts)) * C_CH + c;

    if (gbase >= 0 && gbase + 24 <= T_LEN) {
        // ---------- interior fast path: branch-free ----------
        float va[24];                                   // x[ts-8 .. ts+16)
        const float4* p = (const float4*)(xr + gbase);
        #pragma unroll
        for (int i = 0; i < 6; ++i) {
            float4 v = p[i];
            va[4*i+0] = v.x; va[4*i+1] = v.y; va[4*i+2] = v.z; va[4*i+3] = v.w;
        }

        const float w1s = ((W(5) + W(6)) + (W(7) + W(8))) + W(9);
        float acc[LT];
        #pragma unroll
        for (int i = 0; i < LT; ++i) acc[i] = fmaf(mean, w1s, bs);

        #pragma unroll
        for (int lj = 0; lj < LT + 4; ++lj) {           // feature position j = ts-2+lj
            const float v0 = va[lj+4], v1 = va[lj+5], v2 = va[lj+6], v3 = va[lj+7], v4 = va[lj+8];
            const float s  = ((v0 + v1) + (v2 + v3)) + v4;
            float s2 = v0 * v0;
            s2 = fmaf(v1, v1, s2); s2 = fmaf(v2, v2, s2);
            s2 = fmaf(v3, v3, s2); s2 = fmaf(v4, v4, s2);
            const float mx = fmaxf(fmaxf(fmaxf(v0, v1), fmaxf(v2, v3)), v4);
            const float mn = fminf(fminf(fminf(v0, v1), fminf(v2, v3)), v4);
            const float avg = s * 0.2f;
            float var = fmaf(-avg, avg, s2 * 0.2f);
            var = fmaxf(var, 1e-6f);
            const float sd = __builtin_amdgcn_sqrtf(var);
            const float dm = v2 - avg;
            const float tm = dm * dm * dm;

            #pragma unroll
            for (int dt = -2; dt <= 2; ++dt) {
                const int lt = lj - 2 + dt;             // compile-time after unroll
                if (lt < 0 || lt >= LT) continue;
                const int k = 2 - dt;
                float a = acc[lt];
                a = fmaf(v2, W(k),      a);
                a = fmaf(sd, W(10 + k), a);
                a = fmaf(tm, W(15 + k), a);
                a = fmaf(mx, W(20 + k), a);
                a = fmaf(mn, W(25 + k), a);
                acc[lt] = a;
            }
        }

        #pragma unroll
        for (int lt = 0; lt < LT; ++lt) {
            float o = acc[lt];
            o = fmaxf(o, 0.01f * o);                    // leaky relu
            po[lt * C_CH] = va[lt + 8] + o;             // residual + transposed store
        }
    } else {
        // ---------- edge path (first/last t-blocks): fully guarded ----------
        float va[24];
        #pragma unroll
        for (int i = 0; i < 24; ++i) {
            int g = gbase + i;
            va[i] = (g >= 0 && g < T_LEN) ? xr[g] : 0.f;
        }
        float acc[LT];
        #pragma unroll
        for (int i = 0; i < LT; ++i) acc[i] = bs;

        #pragma unroll
        for (int lj = 0; lj < LT + 4; ++lj) {
            const int j = ts - 2 + lj;
            if (j < 0 || j >= T_LEN) continue;          // conv zero-pad: feature = 0
            float s = 0.f, s2 = 0.f, mx = -INFINITY, mn = INFINITY;
            #pragma unroll
            for (int d = -2; d <= 2; ++d) {
                int gk = j + d;
                if (gk >= 0 && gk < T_LEN) {            // pool validity
                    float v = va[lj + 6 + d];
                    s += v; s2 = fmaf(v, v, s2);
                    mx = fmaxf(mx, v); mn = fminf(mn, v);
                }
            }
            const float avg = s * 0.2f;                 // zero-padded avg: always /5
            float var = fmaf(-avg, avg, s2 * 0.2f);
            var = fmaxf(var, 1e-6f);
            const float sd = __builtin_amdgcn_sqrtf(var);
            const float xc = va[lj + 6];
            const float dm = xc - avg;
            const float tm = dm * dm * dm;

            #pragma unroll
            for (int dt = -2; dt <= 2; ++dt) {
                const int lt = lj - 2 + dt;
                if (lt < 0 || lt >= LT) continue;
                const int k = 2 - dt;
                float a = acc[lt];
                a = fmaf(xc,   W(k),      a);
                a = fmaf(mean, W(5 + k),  a);
                a = fmaf(sd,   W(10 + k), a);
                a = fmaf(tm,   W(15 + k), a);
                a = fmaf(mx,   W(20 + k), a);
                a = fmaf(mn,   W(25 + k), a);
                acc[lt] = a;
            }
        }

        #pragma unroll
        for (int lt = 0; lt < LT; ++lt) {
            float o = acc[lt];
            o = fmaxf(o, 0.01f * o);
            po[lt * C_CH] = va[lt + 8] + o;
        }
    }
    #undef W
}

extern "C" void kernel_launch(void* const* d_in, const int* in_sizes, int n_in,
                              void* d_out, int out_size, void* d_ws, size_t ws_size,
                              hipStream_t stream) {
    const float* x    = (const float*)d_in[0];
    const float* w    = (const float*)d_in[1];
    const float* bias = (const float*)d_in[2];
    float* means = (float*)d_ws;                        // 4096 floats
    float* out   = (float*)d_out;

    row_mean_kernel<<<dim3((B_N * C_CH) / 4), dim3(256), 0, stream>>>(x, means);
    fused_kernel<<<dim3(NT_BLK, C_CH / 64, B_N), dim3(256), 0, stream>>>(x, w, bias, means, out);
}